// Round 1
// baseline (468.065 us; speedup 1.0000x reference)
//
#include <hip/hip_runtime.h>

// GCN 2-layer + mean-pool + FC for MI355X (gfx950).
// Pipeline:
//   deg[i]  = 1 + indeg(i); dis = rsqrt(deg)                 (shared by both layers)
//   agg_x[d] += x[s]*dis[s]*dis[d]   (3 floats/edge scatter)
//   t[i,:]  = relu((agg_x[i]+x[i]*dis[i]^2) @ W1 + b1) @ W2  (fused, W1/W2 in LDS)
//   agg2[d,:] += t[s,:]*dis[s]*dis[d]  (64 floats/edge scatter, lane-coalesced)
//   h2[i,:] = relu(agg2[i,:] + t[i,:]*dis[i]^2 + b2); g = mean_i h2
//   out = g @ Wfc + bfc

__global__ void k_deg_init(float* __restrict__ deg, int n) {
    int i = blockIdx.x * blockDim.x + threadIdx.x;
    if (i < n) deg[i] = 1.0f;   // self-loop
}

__global__ void k_deg_count(const int* __restrict__ dst, float* __restrict__ deg, int E) {
    for (int e = blockIdx.x * blockDim.x + threadIdx.x; e < E; e += gridDim.x * blockDim.x)
        atomicAdd(&deg[dst[e]], 1.0f);
}

__global__ void k_rsqrt(float* __restrict__ deg, int n) {
    int i = blockIdx.x * blockDim.x + threadIdx.x;
    if (i < n) deg[i] = rsqrtf(deg[i]);   // deg >= 1 always
}

__global__ void k_aggx(const int* __restrict__ src, const int* __restrict__ dst,
                       const float* __restrict__ x, const float* __restrict__ dis,
                       float* __restrict__ aggx, int E) {
    for (int e = blockIdx.x * blockDim.x + threadIdx.x; e < E; e += gridDim.x * blockDim.x) {
        int s = src[e], d = dst[e];
        float nrm = dis[s] * dis[d];
        atomicAdd(&aggx[d * 3 + 0], x[s * 3 + 0] * nrm);
        atomicAdd(&aggx[d * 3 + 1], x[s * 3 + 1] * nrm);
        atomicAdd(&aggx[d * 3 + 2], x[s * 3 + 2] * nrm);
    }
}

// t[i,k] = sum_j relu( a(i) . W1[:,j] + b1[j] ) * W2[j,k],  a(i) = aggx[i] + x[i]*dis[i]^2
// One wave per node; lane k owns output feature k. W1/b1/W2 staged in LDS (34 KB).
__global__ void k_node_t(const float* __restrict__ x, const float* __restrict__ dis,
                         const float* __restrict__ aggx,
                         const float* __restrict__ W1, const float* __restrict__ b1,
                         const float* __restrict__ W2,
                         float* __restrict__ t, int n) {
    __shared__ float sW1[3 * 128];
    __shared__ float sb1[128];
    __shared__ float sW2[128 * 64];
    for (int i = threadIdx.x; i < 3 * 128; i += blockDim.x) sW1[i] = W1[i];
    for (int i = threadIdx.x; i < 128;     i += blockDim.x) sb1[i] = b1[i];
    for (int i = threadIdx.x; i < 128 * 64; i += blockDim.x) sW2[i] = W2[i];
    __syncthreads();

    int lane = threadIdx.x & 63;
    int gw = (blockIdx.x * blockDim.x + threadIdx.x) >> 6;
    int nw = (gridDim.x * blockDim.x) >> 6;
    for (int i = gw; i < n; i += nw) {
        float d2 = dis[i] * dis[i];
        float a0 = aggx[i * 3 + 0] + x[i * 3 + 0] * d2;
        float a1 = aggx[i * 3 + 1] + x[i * 3 + 1] * d2;
        float a2 = aggx[i * 3 + 2] + x[i * 3 + 2] * d2;
        float acc = 0.0f;
        #pragma unroll 8
        for (int j = 0; j < 128; ++j) {
            float h = fmaxf(fmaf(a0, sW1[j], fmaf(a1, sW1[128 + j], fmaf(a2, sW1[256 + j], sb1[j]))), 0.0f);
            acc = fmaf(h, sW2[j * 64 + lane], acc);
        }
        t[(size_t)i * 64 + lane] = acc;
    }
}

// agg2[d, lane] += t[s, lane] * dis[s]*dis[d]; one wave per edge (grid-stride).
__global__ void k_agg2(const int* __restrict__ src, const int* __restrict__ dst,
                       const float* __restrict__ dis, const float* __restrict__ t,
                       float* __restrict__ agg2, int E) {
    int lane = threadIdx.x & 63;
    int gw = (blockIdx.x * blockDim.x + threadIdx.x) >> 6;
    int nw = (gridDim.x * blockDim.x) >> 6;
    for (int e = gw; e < E; e += nw) {
        int s = src[e], d = dst[e];
        float nrm = dis[s] * dis[d];
        atomicAdd(&agg2[(size_t)d * 64 + lane], t[(size_t)s * 64 + lane] * nrm);
    }
}

// h2 = relu(agg2 + t*dis^2 + b2); accumulate column sums into g_accum[64].
__global__ void k_h2_mean(const float* __restrict__ t, const float* __restrict__ dis,
                          const float* __restrict__ agg2, const float* __restrict__ b2,
                          float* __restrict__ g_accum, int n) {
    int lane = threadIdx.x & 63;
    float bk = b2[lane];
    int gw = (blockIdx.x * blockDim.x + threadIdx.x) >> 6;
    int nw = (gridDim.x * blockDim.x) >> 6;
    float acc = 0.0f;
    for (int i = gw; i < n; i += nw) {
        float d2 = dis[i] * dis[i];
        float v = agg2[(size_t)i * 64 + lane] + t[(size_t)i * 64 + lane] * d2 + bk;
        acc += fmaxf(v, 0.0f);
    }
    atomicAdd(&g_accum[lane], acc);
}

// out[c] = (1/N) * sum_k g[k] * Wfc[k,c] + bfc[c]; single wave.
__global__ void k_final(const float* __restrict__ g_accum, const float* __restrict__ Wfc,
                        const float* __restrict__ bfc, float* __restrict__ out, float inv_n) {
    int lane = threadIdx.x;   // 0..63
    float gk = g_accum[lane] * inv_n;
    #pragma unroll
    for (int c = 0; c < 3; ++c) {
        float p = gk * Wfc[lane * 3 + c];
        #pragma unroll
        for (int off = 32; off > 0; off >>= 1) p += __shfl_down(p, off);
        if (lane == 0) out[c] = p + bfc[c];
    }
}

extern "C" void kernel_launch(void* const* d_in, const int* in_sizes, int n_in,
                              void* d_out, int out_size, void* d_ws, size_t ws_size,
                              hipStream_t stream) {
    const float* x   = (const float*)d_in[0];
    const int*   ei  = (const int*)d_in[1];
    const float* W1  = (const float*)d_in[2];
    const float* b1  = (const float*)d_in[3];
    const float* W2  = (const float*)d_in[4];
    const float* b2  = (const float*)d_in[5];
    const float* Wfc = (const float*)d_in[6];
    const float* bfc = (const float*)d_in[7];

    const int N = in_sizes[0] / 3;      // 50000
    const int E = in_sizes[1] / 2;      // 600000
    const int* src = ei;
    const int* dst = ei + E;

    float* ws   = (float*)d_ws;
    float* deg  = ws;                       // N floats (becomes dis after k_rsqrt)
    float* aggx = ws + (size_t)N;           // 3N
    float* agg2 = ws + (size_t)4 * N;       // 64N
    float* gacc = ws + (size_t)68 * N;      // 64
    float* t    = ws + (size_t)68 * N + 64; // 64N

    // zero aggx, agg2, gacc in one contiguous memset (t is fully overwritten before read)
    hipMemsetAsync(aggx, 0, ((size_t)67 * N + 64) * sizeof(float), stream);

    k_deg_init<<<(N + 255) / 256, 256, 0, stream>>>(deg, N);
    k_deg_count<<<1024, 256, 0, stream>>>(dst, deg, E);
    k_rsqrt<<<(N + 255) / 256, 256, 0, stream>>>(deg, N);
    k_aggx<<<1024, 256, 0, stream>>>(src, dst, x, deg, aggx, E);
    k_node_t<<<1024, 256, 0, stream>>>(x, deg, aggx, W1, b1, W2, t, N);
    k_agg2<<<4096, 256, 0, stream>>>(src, dst, deg, t, agg2, E);
    k_h2_mean<<<1024, 256, 0, stream>>>(t, deg, agg2, b2, gacc, N);
    k_final<<<1, 64, 0, stream>>>(gacc, Wfc, bfc, (float*)d_out, 1.0f / (float)N);
}